// Round 9
// baseline (237.840 us; speedup 1.0000x reference)
//
#include <hip/hip_runtime.h>
#include <math.h>

// B=2, H=16, S=2048, D=64, fp32 in/out. Flash-style, bf16 MFMA 16x16x32.
// Swapped QK^T -> in-register softmax (cvt_pk + permlane), split-K wave
// groups (R7 base). This round (one structural change): cross-tile software
// pipeline — PV lags QK by one tile. p_frag carries across the barrier;
// iteration t runs QK(t)+softmax(t) and PV(t-1) as independent chains.
// V quad-buffered, K double-buffered; loop unrolled 4x for static indices.
constexpr int Bc = 2, Hc = 16, Sc = 2048, Dc = 64;
constexpr int BQ = 128;  // query rows per block (4 q-bands x 32 rows)
constexpr int BK = 64;   // keys per super-tile (2 halves of 32)
constexpr int NT = Sc / BK;   // 32

constexpr int KWD = 36;  // K row stride (dwords); 16B-aligned rows for b128
constexpr int VWD = 33;  // Vt row stride (dwords); odd -> mixed-parity banks
constexpr int KB_STRIDE = 64 * KWD;        // 2304 dw per K buffer
constexpr int VB_STRIDE = 64 * VWD;        // 2112 dw per V buffer
constexpr int VB_OFF    = 2 * KB_STRIDE;   // 4608
constexpr int SMEM_DW   = VB_OFF + 4 * VB_STRIDE;  // 13056 dw = 52.2 KB

typedef __attribute__((ext_vector_type(8))) short short8v;  // 8 bf16 (4 VGPRs)
typedef __attribute__((ext_vector_type(4))) float f32x4;
typedef __attribute__((ext_vector_type(4))) unsigned int uint4v;

__device__ __forceinline__ unsigned int cvt_pk_bf16(float lo, float hi) {
    unsigned int d;
    asm("v_cvt_pk_bf16_f32 %0, %1, %2" : "=v"(d) : "v"(lo), "v"(hi));
    return d;
}

__global__ __launch_bounds__(512, 4)
void attn_mfma_kernel(const float* __restrict__ Q,
                      const float* __restrict__ K,
                      const float* __restrict__ V,
                      float* __restrict__ O)
{
    __shared__ __align__(16) unsigned int smem[SMEM_DW];

    const int tid  = threadIdx.x;
    const int wave = tid >> 6;
    const int lane = tid & 63;
    const int n    = lane & 15;   // MFMA row/col index within 16
    const int qd   = lane >> 4;   // quad
    const int qw   = wave & 3;    // q-band owner (32 rows each)
    const int kh   = wave >> 2;   // key half: 0 -> keys 0-31, 1 -> keys 32-63

    // ---- XCD-aware swizzle (grid 512): 4 bh per XCD, 16 q-tiles each ----
    const int hid = blockIdx.x;          // 0..511, XCD = hid & 7
    const int hk  = hid >> 3;            // 0..63
    const int bh  = (hid & 7) + 8 * (hk >> 4);
    const int q0  = (hk & 15) * BQ;

    const float* Qg = Q + ((size_t)bh * Sc + q0) * Dc;
    const float* Kg = K + (size_t)bh * Sc * Dc;
    const float* Vg = V + (size_t)bh * Sc * Dc;
    float*       Og = O + ((size_t)bh * Sc + q0) * Dc;

    // ---- Q fragments: two 16-row q-subtiles per wave, scaled by 1/8 ----
    short8v q_frag[2][2];   // [qt][kc]
#pragma unroll
    for (int qt = 0; qt < 2; ++qt)
#pragma unroll
        for (int kc = 0; kc < 2; ++kc) {
            const float* qrow = Qg + (qw * 32 + qt * 16 + n) * Dc + kc * 32 + qd * 8;
            float4 f0 = *reinterpret_cast<const float4*>(qrow);
            float4 f1 = *reinterpret_cast<const float4*>(qrow + 4);
            uint4v u;
            u[0] = cvt_pk_bf16(f0.x * 0.125f, f0.y * 0.125f);
            u[1] = cvt_pk_bf16(f0.z * 0.125f, f0.w * 0.125f);
            u[2] = cvt_pk_bf16(f1.x * 0.125f, f1.y * 0.125f);
            u[3] = cvt_pk_bf16(f1.z * 0.125f, f1.w * 0.125f);
            q_frag[qt][kc] = __builtin_bit_cast(short8v, u);
        }

    const f32x4 z = {0.f, 0.f, 0.f, 0.f};
    f32x4 o_acc[2][4] = {{z, z, z, z}, {z, z, z, z}};
    float l_part[2] = {0.f, 0.f};

    // ---- staging geometry (512 threads, 8 floats K + 8 floats V each) ----
    const int kr  = tid >> 3;            // K row 0..63
    const int kc8 = (tid & 7) << 3;      // K float col 0,8,..56
    const int vkp = tid >> 4;            // V key-pair 0..31
    const int dpb = tid & 15;            // V d-pair base (chunks +16i)

    const float* kbase = Kg + kr * Dc + kc8;
    const float* vbase = Vg + vkp * 2 * Dc + dpb * 2;

    float4 ka[2];
    float2 va[2], vb[2];

    auto load_regs = [&](int kt) {
        const float* Kt = kbase + kt * (BK * Dc);
        const float* Vt = vbase + kt * (BK * Dc);
        ka[0] = *reinterpret_cast<const float4*>(Kt);
        ka[1] = *reinterpret_cast<const float4*>(Kt + 4);
#pragma unroll
        for (int i = 0; i < 2; ++i) {
            va[i] = *reinterpret_cast<const float2*>(Vt + 32 * i);
            vb[i] = *reinterpret_cast<const float2*>(Vt + Dc + 32 * i);
        }
    };
    auto write_lds = [&](int kb, int vbuf) {
        uint4v w;
        w[0] = cvt_pk_bf16(ka[0].x, ka[0].y);
        w[1] = cvt_pk_bf16(ka[0].z, ka[0].w);
        w[2] = cvt_pk_bf16(ka[1].x, ka[1].y);
        w[3] = cvt_pk_bf16(ka[1].z, ka[1].w);
        *reinterpret_cast<uint4v*>(
            &smem[kb * KB_STRIDE + kr * KWD + (tid & 7) * 4]) = w;
        unsigned int* vd = &smem[VB_OFF + vbuf * VB_STRIDE];
#pragma unroll
        for (int i = 0; i < 2; ++i) {
            int dp = dpb + 16 * i;
            vd[(dp * 2)     * VWD + vkp] = cvt_pk_bf16(va[i].x, vb[i].x);
            vd[(dp * 2 + 1) * VWD + vkp] = cvt_pk_bf16(va[i].y, vb[i].y);
        }
    };

    // ---- QK^T + softmax for tile in K buffer kb -> p_frag out ----
    auto qk_softmax = [&](int kb, short8v* pout) {
        f32x4 st[2][2] = {{z, z}, {z, z}};   // [qt][nt]
        const unsigned int* ks = &smem[kb * KB_STRIDE];
        __builtin_amdgcn_s_setprio(1);
#pragma unroll
        for (int nt = 0; nt < 2; ++nt)
#pragma unroll
            for (int kc = 0; kc < 2; ++kc) {
                short8v kf = *reinterpret_cast<const short8v*>(
                    &ks[(kh * 32 + nt * 16 + n) * KWD + kc * 16 + qd * 4]);
#pragma unroll
                for (int qt = 0; qt < 2; ++qt)
                    st[qt][nt] = __builtin_amdgcn_mfma_f32_16x16x32_bf16(
                        kf, q_frag[qt][kc], st[qt][nt], 0, 0, 0);
            }
        __builtin_amdgcn_s_setprio(0);

#pragma unroll
        for (int qt = 0; qt < 2; ++qt) {
            float p00 = __expf(st[qt][0][0]), p01 = __expf(st[qt][0][1]);
            float p02 = __expf(st[qt][0][2]), p03 = __expf(st[qt][0][3]);
            float p10 = __expf(st[qt][1][0]), p11 = __expf(st[qt][1][1]);
            float p12 = __expf(st[qt][1][2]), p13 = __expf(st[qt][1][3]);
            l_part[qt] += ((p00 + p01) + (p02 + p03)) + ((p10 + p11) + (p12 + p13));

            unsigned int x0 = cvt_pk_bf16(p00, p01);
            unsigned int x1 = cvt_pk_bf16(p02, p03);
            unsigned int y0 = cvt_pk_bf16(p10, p11);
            unsigned int y1 = cvt_pk_bf16(p12, p13);
            asm("v_permlane32_swap_b32 %0, %1" : "+v"(x0), "+v"(y0));
            asm("v_permlane16_swap_b32 %0, %1" : "+v"(x0), "+v"(y0));
            asm("v_permlane32_swap_b32 %0, %1" : "+v"(x1), "+v"(y1));
            asm("v_permlane16_swap_b32 %0, %1" : "+v"(x1), "+v"(y1));
            uint4v pu; pu[0] = x0; pu[1] = x1; pu[2] = y0; pu[3] = y1;
            pout[qt] = __builtin_bit_cast(short8v, pu);
        }
    };

    // ---- O += P.V for lagged tile in V buffer vbuf ----
    auto pv = [&](const short8v* pin, int vbuf) {
        const unsigned int* vt = &smem[VB_OFF + vbuf * VB_STRIDE];
        __builtin_amdgcn_s_setprio(1);
#pragma unroll
        for (int dt = 0; dt < 4; ++dt) {
            const unsigned int* vrow = vt + (dt * 16 + n) * VWD + kh * 16 + qd * 4;
            uint4v vu;
            vu[0] = vrow[0]; vu[1] = vrow[1]; vu[2] = vrow[2]; vu[3] = vrow[3];
            short8v vf = __builtin_bit_cast(short8v, vu);
#pragma unroll
            for (int qt = 0; qt < 2; ++qt)
                o_acc[qt][dt] = __builtin_amdgcn_mfma_f32_16x16x32_bf16(
                    pin[qt], vf, o_acc[qt][dt], 0, 0, 0);
        }
        __builtin_amdgcn_s_setprio(0);
    };

    // ---- prologue: tile 0 staged, tile 1 in registers ----
    load_regs(0);
    write_lds(0, 0);
    load_regs(1);
    __syncthreads();

    short8v pA[2], pB[2];

    for (int it = 0; it < NT / 4; ++it) {
        const int kt0  = it * 4;
        const bool more = (it + 1 < NT / 4);
        // u=0: tile kt0 (Kb0); PV(kt0-1) from Vb3
        qk_softmax(0, pA);
        if (kt0 > 0) pv(pB, 3);
        write_lds(1, 1);          // tile kt0+1
        load_regs(kt0 + 2);
        __syncthreads();
        // u=1: tile kt0+1 (Kb1); PV(kt0) from Vb0
        qk_softmax(1, pB);
        pv(pA, 0);
        write_lds(0, 2);          // tile kt0+2
        load_regs(kt0 + 3);
        __syncthreads();
        // u=2: tile kt0+2 (Kb0); PV(kt0+1) from Vb1
        qk_softmax(0, pA);
        pv(pB, 1);
        write_lds(1, 3);          // tile kt0+3
        if (more) load_regs(kt0 + 4);
        __syncthreads();
        // u=3: tile kt0+3 (Kb1); PV(kt0+2) from Vb2
        qk_softmax(1, pB);
        pv(pA, 2);
        if (more) { write_lds(0, 0); load_regs(kt0 + 5); }  // tile kt0+4
        __syncthreads();
    }
    // final PV: tile NT-1 from Vb3
    pv(pB, 3);

    // ---- split-K merge: group B publishes partials, group A adds ----
    // merge region = smem dw 0..8703; Vb3 lives at dw 10944+ (no overlap)
    float* mo = reinterpret_cast<float*>(smem);           // 8192 floats
    float* ml = reinterpret_cast<float*>(smem + 8192);    // 512 floats
    if (kh == 1) {
#pragma unroll
        for (int qt = 0; qt < 2; ++qt) {
#pragma unroll
            for (int dt = 0; dt < 4; ++dt)
                *reinterpret_cast<f32x4*>(
                    &mo[(((qw * 64 + lane) * 2 + qt) * 4 + dt) * 4]) = o_acc[qt][dt];
            ml[(qw * 64 + lane) * 2 + qt] = l_part[qt];
        }
    }
    __syncthreads();
    if (kh == 0) {
#pragma unroll
        for (int qt = 0; qt < 2; ++qt) {
#pragma unroll
            for (int dt = 0; dt < 4; ++dt)
                o_acc[qt][dt] += *reinterpret_cast<const f32x4*>(
                    &mo[(((qw * 64 + lane) * 2 + qt) * 4 + dt) * 4]);
            l_part[qt] += ml[(qw * 64 + lane) * 2 + qt];
        }

        // ---- epilogue: reduce l across quads, O/l (per q-subtile) ----
#pragma unroll
        for (int qt = 0; qt < 2; ++qt) {
            float lp = l_part[qt];
            lp += __shfl_xor(lp, 16, 64);
            lp += __shfl_xor(lp, 32, 64);   // lane (n,qd): l for q-row n
#pragma unroll
            for (int r = 0; r < 4; ++r) {
                float lr  = __shfl(lp, qd * 4 + r, 64);  // l for q-row qd*4+r
                float inv = 1.0f / lr;
#pragma unroll
                for (int dt = 0; dt < 4; ++dt) {
                    Og[(qw * 32 + qt * 16 + qd * 4 + r) * Dc + dt * 16 + n] =
                        o_acc[qt][dt][r] * inv;
                }
            }
        }
    }
}

extern "C" void kernel_launch(void* const* d_in, const int* in_sizes, int n_in,
                              void* d_out, int out_size, void* d_ws, size_t ws_size,
                              hipStream_t stream) {
    const float* q = (const float*)d_in[0];
    const float* k = (const float*)d_in[1];
    const float* v = (const float*)d_in[2];
    float*       o = (float*)d_out;

    dim3 grid((Sc / BQ) * Bc * Hc);   // 512, 1D for XCD swizzle
    attn_mfma_kernel<<<grid, 512, 0, stream>>>(q, k, v, o);
}

// Round 10
// 235.898 us; speedup vs baseline: 1.0082x; 1.0082x over previous
//
#include <hip/hip_runtime.h>
#include <math.h>

// B=2, H=16, S=2048, D=64, fp32 in/out. Flash-style, bf16 MFMA 16x16x32.
// Swapped QK^T -> in-register softmax (cvt_pk + permlane), split-K wave
// groups. R9 schedule (PV lags QK by one tile; V quad-buffered, K double-
// buffered, 4x-unrolled static buffer indices) with the scratch-spill
// fixed: P fragments travel as a by-value struct (PFrag), never as
// address-taken arrays.
constexpr int Bc = 2, Hc = 16, Sc = 2048, Dc = 64;
constexpr int BQ = 128;  // query rows per block (4 q-bands x 32 rows)
constexpr int BK = 64;   // keys per super-tile (2 halves of 32)
constexpr int NT = Sc / BK;   // 32

constexpr int KWD = 36;  // K row stride (dwords); 16B-aligned rows for b128
constexpr int VWD = 33;  // Vt row stride (dwords); odd -> mixed-parity banks
constexpr int KB_STRIDE = 64 * KWD;        // 2304 dw per K buffer
constexpr int VB_STRIDE = 64 * VWD;        // 2112 dw per V buffer
constexpr int VB_OFF    = 2 * KB_STRIDE;   // 4608
constexpr int SMEM_DW   = VB_OFF + 4 * VB_STRIDE;  // 13056 dw = 52.2 KB

typedef __attribute__((ext_vector_type(8))) short short8v;  // 8 bf16 (4 VGPRs)
typedef __attribute__((ext_vector_type(4))) float f32x4;
typedef __attribute__((ext_vector_type(4))) unsigned int uint4v;

struct PFrag { short8v p0, p1; };   // by-value carrier: stays in VGPRs

__device__ __forceinline__ unsigned int cvt_pk_bf16(float lo, float hi) {
    unsigned int d;
    asm("v_cvt_pk_bf16_f32 %0, %1, %2" : "=v"(d) : "v"(lo), "v"(hi));
    return d;
}

__global__ __launch_bounds__(512, 4)
void attn_mfma_kernel(const float* __restrict__ Q,
                      const float* __restrict__ K,
                      const float* __restrict__ V,
                      float* __restrict__ O)
{
    __shared__ __align__(16) unsigned int smem[SMEM_DW];

    const int tid  = threadIdx.x;
    const int wave = tid >> 6;
    const int lane = tid & 63;
    const int n    = lane & 15;   // MFMA row/col index within 16
    const int qd   = lane >> 4;   // quad
    const int qw   = wave & 3;    // q-band owner (32 rows each)
    const int kh   = wave >> 2;   // key half: 0 -> keys 0-31, 1 -> keys 32-63

    // ---- XCD-aware swizzle (grid 512): 4 bh per XCD, 16 q-tiles each ----
    const int hid = blockIdx.x;          // 0..511, XCD = hid & 7
    const int hk  = hid >> 3;            // 0..63
    const int bh  = (hid & 7) + 8 * (hk >> 4);
    const int q0  = (hk & 15) * BQ;

    const float* Qg = Q + ((size_t)bh * Sc + q0) * Dc;
    const float* Kg = K + (size_t)bh * Sc * Dc;
    const float* Vg = V + (size_t)bh * Sc * Dc;
    float*       Og = O + ((size_t)bh * Sc + q0) * Dc;

    // ---- Q fragments: two 16-row q-subtiles per wave, scaled by 1/8 ----
    short8v q_frag[2][2];   // [qt][kc]
#pragma unroll
    for (int qt = 0; qt < 2; ++qt)
#pragma unroll
        for (int kc = 0; kc < 2; ++kc) {
            const float* qrow = Qg + (qw * 32 + qt * 16 + n) * Dc + kc * 32 + qd * 8;
            float4 f0 = *reinterpret_cast<const float4*>(qrow);
            float4 f1 = *reinterpret_cast<const float4*>(qrow + 4);
            uint4v u;
            u[0] = cvt_pk_bf16(f0.x * 0.125f, f0.y * 0.125f);
            u[1] = cvt_pk_bf16(f0.z * 0.125f, f0.w * 0.125f);
            u[2] = cvt_pk_bf16(f1.x * 0.125f, f1.y * 0.125f);
            u[3] = cvt_pk_bf16(f1.z * 0.125f, f1.w * 0.125f);
            q_frag[qt][kc] = __builtin_bit_cast(short8v, u);
        }

    const f32x4 z = {0.f, 0.f, 0.f, 0.f};
    f32x4 o_acc[2][4] = {{z, z, z, z}, {z, z, z, z}};
    float l_part[2] = {0.f, 0.f};

    // ---- staging geometry (512 threads, 8 floats K + 8 floats V each) ----
    const int kr  = tid >> 3;            // K row 0..63
    const int kc8 = (tid & 7) << 3;      // K float col 0,8,..56
    const int vkp = tid >> 4;            // V key-pair 0..31
    const int dpb = tid & 15;            // V d-pair base (chunks +16i)

    const float* kbase = Kg + kr * Dc + kc8;
    const float* vbase = Vg + vkp * 2 * Dc + dpb * 2;

    float4 ka[2];
    float2 va[2], vb[2];

    auto load_regs = [&](int kt) {
        const float* Kt = kbase + kt * (BK * Dc);
        const float* Vt = vbase + kt * (BK * Dc);
        ka[0] = *reinterpret_cast<const float4*>(Kt);
        ka[1] = *reinterpret_cast<const float4*>(Kt + 4);
#pragma unroll
        for (int i = 0; i < 2; ++i) {
            va[i] = *reinterpret_cast<const float2*>(Vt + 32 * i);
            vb[i] = *reinterpret_cast<const float2*>(Vt + Dc + 32 * i);
        }
    };
    auto write_lds = [&](int kb, int vbuf) {
        uint4v w;
        w[0] = cvt_pk_bf16(ka[0].x, ka[0].y);
        w[1] = cvt_pk_bf16(ka[0].z, ka[0].w);
        w[2] = cvt_pk_bf16(ka[1].x, ka[1].y);
        w[3] = cvt_pk_bf16(ka[1].z, ka[1].w);
        *reinterpret_cast<uint4v*>(
            &smem[kb * KB_STRIDE + kr * KWD + (tid & 7) * 4]) = w;
        unsigned int* vd = &smem[VB_OFF + vbuf * VB_STRIDE];
#pragma unroll
        for (int i = 0; i < 2; ++i) {
            int dp = dpb + 16 * i;
            vd[(dp * 2)     * VWD + vkp] = cvt_pk_bf16(va[i].x, vb[i].x);
            vd[(dp * 2 + 1) * VWD + vkp] = cvt_pk_bf16(va[i].y, vb[i].y);
        }
    };

    // ---- QK^T + softmax for tile in K buffer kb -> PFrag by value ----
    auto qk_softmax = [&](int kb) -> PFrag {
        f32x4 st[2][2] = {{z, z}, {z, z}};   // [qt][nt]
        const unsigned int* ks = &smem[kb * KB_STRIDE];
        __builtin_amdgcn_s_setprio(1);
#pragma unroll
        for (int nt = 0; nt < 2; ++nt)
#pragma unroll
            for (int kc = 0; kc < 2; ++kc) {
                short8v kf = *reinterpret_cast<const short8v*>(
                    &ks[(kh * 32 + nt * 16 + n) * KWD + kc * 16 + qd * 4]);
#pragma unroll
                for (int qt = 0; qt < 2; ++qt)
                    st[qt][nt] = __builtin_amdgcn_mfma_f32_16x16x32_bf16(
                        kf, q_frag[qt][kc], st[qt][nt], 0, 0, 0);
            }
        __builtin_amdgcn_s_setprio(0);

        PFrag pf;
#pragma unroll
        for (int qt = 0; qt < 2; ++qt) {
            float p00 = __expf(st[qt][0][0]), p01 = __expf(st[qt][0][1]);
            float p02 = __expf(st[qt][0][2]), p03 = __expf(st[qt][0][3]);
            float p10 = __expf(st[qt][1][0]), p11 = __expf(st[qt][1][1]);
            float p12 = __expf(st[qt][1][2]), p13 = __expf(st[qt][1][3]);
            l_part[qt] += ((p00 + p01) + (p02 + p03)) + ((p10 + p11) + (p12 + p13));

            unsigned int x0 = cvt_pk_bf16(p00, p01);
            unsigned int x1 = cvt_pk_bf16(p02, p03);
            unsigned int y0 = cvt_pk_bf16(p10, p11);
            unsigned int y1 = cvt_pk_bf16(p12, p13);
            asm("v_permlane32_swap_b32 %0, %1" : "+v"(x0), "+v"(y0));
            asm("v_permlane16_swap_b32 %0, %1" : "+v"(x0), "+v"(y0));
            asm("v_permlane32_swap_b32 %0, %1" : "+v"(x1), "+v"(y1));
            asm("v_permlane16_swap_b32 %0, %1" : "+v"(x1), "+v"(y1));
            uint4v pu; pu[0] = x0; pu[1] = x1; pu[2] = y0; pu[3] = y1;
            if (qt == 0) pf.p0 = __builtin_bit_cast(short8v, pu);
            else         pf.p1 = __builtin_bit_cast(short8v, pu);
        }
        return pf;
    };

    // ---- O += P.V for lagged tile in V buffer vbuf (PFrag by value) ----
    auto pv = [&](PFrag pf, int vbuf) {
        const unsigned int* vt = &smem[VB_OFF + vbuf * VB_STRIDE];
        __builtin_amdgcn_s_setprio(1);
#pragma unroll
        for (int dt = 0; dt < 4; ++dt) {
            const unsigned int* vrow = vt + (dt * 16 + n) * VWD + kh * 16 + qd * 4;
            uint4v vu;
            vu[0] = vrow[0]; vu[1] = vrow[1]; vu[2] = vrow[2]; vu[3] = vrow[3];
            short8v vf = __builtin_bit_cast(short8v, vu);
            o_acc[0][dt] = __builtin_amdgcn_mfma_f32_16x16x32_bf16(
                pf.p0, vf, o_acc[0][dt], 0, 0, 0);
            o_acc[1][dt] = __builtin_amdgcn_mfma_f32_16x16x32_bf16(
                pf.p1, vf, o_acc[1][dt], 0, 0, 0);
        }
        __builtin_amdgcn_s_setprio(0);
    };

    // ---- prologue: tile 0 staged, tile 1 in registers ----
    load_regs(0);
    write_lds(0, 0);
    load_regs(1);
    __syncthreads();

    PFrag pA, pB;

    for (int it = 0; it < NT / 4; ++it) {
        const int kt0   = it * 4;
        const bool more = (it + 1 < NT / 4);
        // u=0: QK(kt0) from Kb0; PV(kt0-1) from Vb3
        pA = qk_softmax(0);
        if (kt0 > 0) pv(pB, 3);
        write_lds(1, 1);          // tile kt0+1
        load_regs(kt0 + 2);
        __syncthreads();
        // u=1: QK(kt0+1) from Kb1; PV(kt0) from Vb0
        pB = qk_softmax(1);
        pv(pA, 0);
        write_lds(0, 2);          // tile kt0+2
        load_regs(kt0 + 3);
        __syncthreads();
        // u=2: QK(kt0+2) from Kb0; PV(kt0+1) from Vb1
        pA = qk_softmax(0);
        pv(pB, 1);
        write_lds(1, 3);          // tile kt0+3
        if (more) load_regs(kt0 + 4);
        __syncthreads();
        // u=3: QK(kt0+3) from Kb1; PV(kt0+2) from Vb2
        pB = qk_softmax(1);
        pv(pA, 2);
        if (more) { write_lds(0, 0); load_regs(kt0 + 5); }  // tile kt0+4
        __syncthreads();
    }
    // final PV: tile NT-1 from Vb3
    pv(pB, 3);

    // ---- split-K merge: group B publishes partials, group A adds ----
    // merge region = smem dw 0..8703; Vb3 lives at dw 10944+ (no overlap)
    float* mo = reinterpret_cast<float*>(smem);           // 8192 floats
    float* ml = reinterpret_cast<float*>(smem + 8192);    // 512 floats
    if (kh == 1) {
#pragma unroll
        for (int qt = 0; qt < 2; ++qt) {
#pragma unroll
            for (int dt = 0; dt < 4; ++dt)
                *reinterpret_cast<f32x4*>(
                    &mo[(((qw * 64 + lane) * 2 + qt) * 4 + dt) * 4]) = o_acc[qt][dt];
            ml[(qw * 64 + lane) * 2 + qt] = l_part[qt];
        }
    }
    __syncthreads();
    if (kh == 0) {
#pragma unroll
        for (int qt = 0; qt < 2; ++qt) {
#pragma unroll
            for (int dt = 0; dt < 4; ++dt)
                o_acc[qt][dt] += *reinterpret_cast<const f32x4*>(
                    &mo[(((qw * 64 + lane) * 2 + qt) * 4 + dt) * 4]);
            l_part[qt] += ml[(qw * 64 + lane) * 2 + qt];
        }

        // ---- epilogue: reduce l across quads, O/l (per q-subtile) ----
#pragma unroll
        for (int qt = 0; qt < 2; ++qt) {
            float lp = l_part[qt];
            lp += __shfl_xor(lp, 16, 64);
            lp += __shfl_xor(lp, 32, 64);   // lane (n,qd): l for q-row n
#pragma unroll
            for (int r = 0; r < 4; ++r) {
                float lr  = __shfl(lp, qd * 4 + r, 64);  // l for q-row qd*4+r
                float inv = 1.0f / lr;
#pragma unroll
                for (int dt = 0; dt < 4; ++dt) {
                    Og[(qw * 32 + qt * 16 + qd * 4 + r) * Dc + dt * 16 + n] =
                        o_acc[qt][dt][r] * inv;
                }
            }
        }
    }
}

extern "C" void kernel_launch(void* const* d_in, const int* in_sizes, int n_in,
                              void* d_out, int out_size, void* d_ws, size_t ws_size,
                              hipStream_t stream) {
    const float* q = (const float*)d_in[0];
    const float* k = (const float*)d_in[1];
    const float* v = (const float*)d_in[2];
    float*       o = (float*)d_out;

    dim3 grid((Sc / BQ) * Bc * Hc);   // 512, 1D for XCD swizzle
    attn_mfma_kernel<<<grid, 512, 0, stream>>>(q, k, v, o);
}

// Round 11
// 132.621 us; speedup vs baseline: 1.7934x; 1.7787x over previous
//
#include <hip/hip_runtime.h>
#include <math.h>

// B=2, H=16, S=2048, D=64, fp32 in/out. Flash-style, bf16 MFMA 16x16x32.
// Swapped QK^T -> in-register softmax (cvt_pk + permlane), split-K wave
// groups. PV lags QK by one tile (cross-tile pipeline). This round: the
// whole loop body is HAND-INLINED in a rolled loop (no lambdas -> no
// inlining failure -> no stack traffic, the R9/R10 bug). Runtime buffer
// indices are LDS address math only; P carried in named VGPR vectors.
constexpr int Bc = 2, Hc = 16, Sc = 2048, Dc = 64;
constexpr int BQ = 128;  // query rows per block (4 q-bands x 32 rows)
constexpr int BK = 64;   // keys per super-tile (2 halves of 32)
constexpr int NT = Sc / BK;   // 32

constexpr int KWD = 36;  // K row stride (dwords); 16B-aligned rows for b128
constexpr int VWD = 33;  // Vt row stride (dwords); odd -> mixed-parity banks
constexpr int KB_STRIDE = 64 * KWD;        // 2304 dw per K buffer (x2)
constexpr int VB_STRIDE = 64 * VWD;        // 2112 dw per V buffer (x4)
constexpr int VB_OFF    = 2 * KB_STRIDE;   // 4608
constexpr int SMEM_DW   = VB_OFF + 4 * VB_STRIDE;  // 13056 dw = 52.2 KB

typedef __attribute__((ext_vector_type(8))) short short8v;  // 8 bf16 (4 VGPRs)
typedef __attribute__((ext_vector_type(4))) float f32x4;
typedef __attribute__((ext_vector_type(4))) unsigned int uint4v;

__device__ __forceinline__ unsigned int cvt_pk_bf16(float lo, float hi) {
    unsigned int d;
    asm("v_cvt_pk_bf16_f32 %0, %1, %2" : "=v"(d) : "v"(lo), "v"(hi));
    return d;
}

__global__ __launch_bounds__(512, 4)
void attn_mfma_kernel(const float* __restrict__ Q,
                      const float* __restrict__ K,
                      const float* __restrict__ V,
                      float* __restrict__ O)
{
    __shared__ __align__(16) unsigned int smem[SMEM_DW];

    const int tid  = threadIdx.x;
    const int wave = tid >> 6;
    const int lane = tid & 63;
    const int n    = lane & 15;   // MFMA row/col index within 16
    const int qd   = lane >> 4;   // quad
    const int qw   = wave & 3;    // q-band owner (32 rows each)
    const int kh   = wave >> 2;   // key half: 0 -> keys 0-31, 1 -> keys 32-63

    // ---- XCD-aware swizzle (grid 512): 4 bh per XCD, 16 q-tiles each ----
    const int hid = blockIdx.x;          // 0..511, XCD = hid & 7
    const int hk  = hid >> 3;            // 0..63
    const int bh  = (hid & 7) + 8 * (hk >> 4);
    const int q0  = (hk & 15) * BQ;

    const float* Qg = Q + ((size_t)bh * Sc + q0) * Dc;
    const float* Kg = K + (size_t)bh * Sc * Dc;
    const float* Vg = V + (size_t)bh * Sc * Dc;
    float*       Og = O + ((size_t)bh * Sc + q0) * Dc;

    // ---- Q fragments: two 16-row q-subtiles per wave, scaled by 1/8 ----
    short8v q_frag[2][2];   // [qt][kc]
#pragma unroll
    for (int qt = 0; qt < 2; ++qt)
#pragma unroll
        for (int kc = 0; kc < 2; ++kc) {
            const float* qrow = Qg + (qw * 32 + qt * 16 + n) * Dc + kc * 32 + qd * 8;
            float4 f0 = *reinterpret_cast<const float4*>(qrow);
            float4 f1 = *reinterpret_cast<const float4*>(qrow + 4);
            uint4v u;
            u[0] = cvt_pk_bf16(f0.x * 0.125f, f0.y * 0.125f);
            u[1] = cvt_pk_bf16(f0.z * 0.125f, f0.w * 0.125f);
            u[2] = cvt_pk_bf16(f1.x * 0.125f, f1.y * 0.125f);
            u[3] = cvt_pk_bf16(f1.z * 0.125f, f1.w * 0.125f);
            q_frag[qt][kc] = __builtin_bit_cast(short8v, u);
        }

    const f32x4 z = {0.f, 0.f, 0.f, 0.f};
    f32x4 o_acc[2][4] = {{z, z, z, z}, {z, z, z, z}};
    float l_part[2] = {0.f, 0.f};

    // ---- staging geometry (512 threads, 8 floats K + 8 floats V each) ----
    const int kr  = tid >> 3;            // K row 0..63
    const int kc8 = (tid & 7) << 3;      // K float col 0,8,..56
    const int vkp = tid >> 4;            // V key-pair 0..31
    const int dpb = tid & 15;            // V d-pair base (chunks +16i)

    const float* kbase = Kg + kr * Dc + kc8;
    const float* vbase = Vg + vkp * 2 * Dc + dpb * 2;

    float4 ka0, ka1;
    float2 va0, va1, vb0, vb1;

    // ---- prologue: load tile0, stage it, load tile1; zero Vb3 + pPrev ----
    {
        const float* Kt = kbase;
        const float* Vt = vbase;
        ka0 = *reinterpret_cast<const float4*>(Kt);
        ka1 = *reinterpret_cast<const float4*>(Kt + 4);
        va0 = *reinterpret_cast<const float2*>(Vt);
        vb0 = *reinterpret_cast<const float2*>(Vt + Dc);
        va1 = *reinterpret_cast<const float2*>(Vt + 32);
        vb1 = *reinterpret_cast<const float2*>(Vt + Dc + 32);
    }
    {
        uint4v w;
        w[0] = cvt_pk_bf16(ka0.x, ka0.y);
        w[1] = cvt_pk_bf16(ka0.z, ka0.w);
        w[2] = cvt_pk_bf16(ka1.x, ka1.y);
        w[3] = cvt_pk_bf16(ka1.z, ka1.w);
        *reinterpret_cast<uint4v*>(&smem[kr * KWD + (tid & 7) * 4]) = w;
        unsigned int* vd = &smem[VB_OFF];
        vd[(dpb * 2)            * VWD + vkp] = cvt_pk_bf16(va0.x, vb0.x);
        vd[(dpb * 2 + 1)        * VWD + vkp] = cvt_pk_bf16(va0.y, vb0.y);
        vd[((dpb + 16) * 2)     * VWD + vkp] = cvt_pk_bf16(va1.x, vb1.x);
        vd[((dpb + 16) * 2 + 1) * VWD + vkp] = cvt_pk_bf16(va1.y, vb1.y);
    }
    {
        const float* Kt = kbase + BK * Dc;
        const float* Vt = vbase + BK * Dc;
        ka0 = *reinterpret_cast<const float4*>(Kt);
        ka1 = *reinterpret_cast<const float4*>(Kt + 4);
        va0 = *reinterpret_cast<const float2*>(Vt);
        vb0 = *reinterpret_cast<const float2*>(Vt + Dc);
        va1 = *reinterpret_cast<const float2*>(Vt + 32);
        vb1 = *reinterpret_cast<const float2*>(Vt + Dc + 32);
    }
    // zero Vb3 (read by the harmless kt=0 PV with P=0)
    for (int i = tid; i < VB_STRIDE; i += 512)
        smem[VB_OFF + 3 * VB_STRIDE + i] = 0u;
    __syncthreads();

    short8v pp0 = {0,0,0,0,0,0,0,0}, pp1 = {0,0,0,0,0,0,0,0};

    for (int kt = 0; kt < NT; ++kt) {
        // ================= QK^T from Kb[kt&1] =================
        const unsigned int* ks = &smem[(kt & 1) * KB_STRIDE];
        f32x4 st[2][2] = {{z, z}, {z, z}};   // [qt][nt]
        __builtin_amdgcn_s_setprio(1);
#pragma unroll
        for (int nt = 0; nt < 2; ++nt)
#pragma unroll
            for (int kc = 0; kc < 2; ++kc) {
                short8v kf = *reinterpret_cast<const short8v*>(
                    &ks[(kh * 32 + nt * 16 + n) * KWD + kc * 16 + qd * 4]);
#pragma unroll
                for (int qt = 0; qt < 2; ++qt)
                    st[qt][nt] = __builtin_amdgcn_mfma_f32_16x16x32_bf16(
                        kf, q_frag[qt][kc], st[qt][nt], 0, 0, 0);
            }
        __builtin_amdgcn_s_setprio(0);

        // ================= PV of PREVIOUS tile from Vb[(kt-1)&3] =========
        // (kt=0: pp==0 and Vb3 zeroed -> contributes nothing)
        {
            const unsigned int* vt = &smem[VB_OFF + ((kt - 1) & 3) * VB_STRIDE];
            __builtin_amdgcn_s_setprio(1);
#pragma unroll
            for (int dt = 0; dt < 4; ++dt) {
                const unsigned int* vrow = vt + (dt * 16 + n) * VWD + kh * 16 + qd * 4;
                uint4v vu;
                vu[0] = vrow[0]; vu[1] = vrow[1]; vu[2] = vrow[2]; vu[3] = vrow[3];
                short8v vf = __builtin_bit_cast(short8v, vu);
                o_acc[0][dt] = __builtin_amdgcn_mfma_f32_16x16x32_bf16(
                    pp0, vf, o_acc[0][dt], 0, 0, 0);
                o_acc[1][dt] = __builtin_amdgcn_mfma_f32_16x16x32_bf16(
                    pp1, vf, o_acc[1][dt], 0, 0, 0);
            }
            __builtin_amdgcn_s_setprio(0);
        }

        // ================= softmax(st) -> pCur ===========================
        short8v pc0, pc1;
#pragma unroll
        for (int qt = 0; qt < 2; ++qt) {
            float p00 = __expf(st[qt][0][0]), p01 = __expf(st[qt][0][1]);
            float p02 = __expf(st[qt][0][2]), p03 = __expf(st[qt][0][3]);
            float p10 = __expf(st[qt][1][0]), p11 = __expf(st[qt][1][1]);
            float p12 = __expf(st[qt][1][2]), p13 = __expf(st[qt][1][3]);
            l_part[qt] += ((p00 + p01) + (p02 + p03)) + ((p10 + p11) + (p12 + p13));

            unsigned int x0 = cvt_pk_bf16(p00, p01);
            unsigned int x1 = cvt_pk_bf16(p02, p03);
            unsigned int y0 = cvt_pk_bf16(p10, p11);
            unsigned int y1 = cvt_pk_bf16(p12, p13);
            asm("v_permlane32_swap_b32 %0, %1" : "+v"(x0), "+v"(y0));
            asm("v_permlane16_swap_b32 %0, %1" : "+v"(x0), "+v"(y0));
            asm("v_permlane32_swap_b32 %0, %1" : "+v"(x1), "+v"(y1));
            asm("v_permlane16_swap_b32 %0, %1" : "+v"(x1), "+v"(y1));
            uint4v pu; pu[0] = x0; pu[1] = x1; pu[2] = y0; pu[3] = y1;
            if (qt == 0) pc0 = __builtin_bit_cast(short8v, pu);
            else         pc1 = __builtin_bit_cast(short8v, pu);
        }

        // ================= stage tile kt+1 -> Kb[(kt+1)&1], Vb[(kt+1)&3] =
        {
            uint4v w;
            w[0] = cvt_pk_bf16(ka0.x, ka0.y);
            w[1] = cvt_pk_bf16(ka0.z, ka0.w);
            w[2] = cvt_pk_bf16(ka1.x, ka1.y);
            w[3] = cvt_pk_bf16(ka1.z, ka1.w);
            *reinterpret_cast<uint4v*>(
                &smem[((kt + 1) & 1) * KB_STRIDE + kr * KWD + (tid & 7) * 4]) = w;
            unsigned int* vd = &smem[VB_OFF + ((kt + 1) & 3) * VB_STRIDE];
            vd[(dpb * 2)            * VWD + vkp] = cvt_pk_bf16(va0.x, vb0.x);
            vd[(dpb * 2 + 1)        * VWD + vkp] = cvt_pk_bf16(va0.y, vb0.y);
            vd[((dpb + 16) * 2)     * VWD + vkp] = cvt_pk_bf16(va1.x, vb1.x);
            vd[((dpb + 16) * 2 + 1) * VWD + vkp] = cvt_pk_bf16(va1.y, vb1.y);
        }

        // ================= load tile kt+2 (clamped) ======================
        {
            const int lt = (kt + 2 < NT) ? kt + 2 : NT - 1;
            const float* Kt = kbase + lt * (BK * Dc);
            const float* Vt = vbase + lt * (BK * Dc);
            ka0 = *reinterpret_cast<const float4*>(Kt);
            ka1 = *reinterpret_cast<const float4*>(Kt + 4);
            va0 = *reinterpret_cast<const float2*>(Vt);
            vb0 = *reinterpret_cast<const float2*>(Vt + Dc);
            va1 = *reinterpret_cast<const float2*>(Vt + 32);
            vb1 = *reinterpret_cast<const float2*>(Vt + Dc + 32);
        }

        __syncthreads();
        pp0 = pc0; pp1 = pc1;
    }

    // ---- final PV: tile NT-1 from Vb[(NT-1)&3] ----
    {
        const unsigned int* vt = &smem[VB_OFF + ((NT - 1) & 3) * VB_STRIDE];
#pragma unroll
        for (int dt = 0; dt < 4; ++dt) {
            const unsigned int* vrow = vt + (dt * 16 + n) * VWD + kh * 16 + qd * 4;
            uint4v vu;
            vu[0] = vrow[0]; vu[1] = vrow[1]; vu[2] = vrow[2]; vu[3] = vrow[3];
            short8v vf = __builtin_bit_cast(short8v, vu);
            o_acc[0][dt] = __builtin_amdgcn_mfma_f32_16x16x32_bf16(
                pp0, vf, o_acc[0][dt], 0, 0, 0);
            o_acc[1][dt] = __builtin_amdgcn_mfma_f32_16x16x32_bf16(
                pp1, vf, o_acc[1][dt], 0, 0, 0);
        }
    }

    // ---- split-K merge: group B publishes partials, group A adds ----
    // merge region = smem dw 0..8703; Vb3 (10944+) untouched by it
    float* mo = reinterpret_cast<float*>(smem);           // 8192 floats
    float* ml = reinterpret_cast<float*>(smem + 8192);    // 512 floats
    __syncthreads();   // all PV reads done before merge overwrites buffers
    if (kh == 1) {
#pragma unroll
        for (int qt = 0; qt < 2; ++qt) {
#pragma unroll
            for (int dt = 0; dt < 4; ++dt)
                *reinterpret_cast<f32x4*>(
                    &mo[(((qw * 64 + lane) * 2 + qt) * 4 + dt) * 4]) = o_acc[qt][dt];
            ml[(qw * 64 + lane) * 2 + qt] = l_part[qt];
        }
    }
    __syncthreads();
    if (kh == 0) {
#pragma unroll
        for (int qt = 0; qt < 2; ++qt) {
#pragma unroll
            for (int dt = 0; dt < 4; ++dt)
                o_acc[qt][dt] += *reinterpret_cast<const f32x4*>(
                    &mo[(((qw * 64 + lane) * 2 + qt) * 4 + dt) * 4]);
            l_part[qt] += ml[(qw * 64 + lane) * 2 + qt];
        }

        // ---- epilogue: reduce l across quads, O/l (per q-subtile) ----
#pragma unroll
        for (int qt = 0; qt < 2; ++qt) {
            float lp = l_part[qt];
            lp += __shfl_xor(lp, 16, 64);
            lp += __shfl_xor(lp, 32, 64);   // lane (n,qd): l for q-row n
#pragma unroll
            for (int r = 0; r < 4; ++r) {
                float lr  = __shfl(lp, qd * 4 + r, 64);  // l for q-row qd*4+r
                float inv = 1.0f / lr;
#pragma unroll
                for (int dt = 0; dt < 4; ++dt) {
                    Og[(qw * 32 + qt * 16 + qd * 4 + r) * Dc + dt * 16 + n] =
                        o_acc[qt][dt][r] * inv;
                }
            }
        }
    }
}

extern "C" void kernel_launch(void* const* d_in, const int* in_sizes, int n_in,
                              void* d_out, int out_size, void* d_ws, size_t ws_size,
                              hipStream_t stream) {
    const float* q = (const float*)d_in[0];
    const float* k = (const float*)d_in[1];
    const float* v = (const float*)d_in[2];
    float*       o = (float*)d_out;

    dim3 grid((Sc / BQ) * Bc * Hc);   // 512, 1D for XCD swizzle
    attn_mfma_kernel<<<grid, 512, 0, stream>>>(q, k, v, o);
}